// Round 11
// baseline (879.511 us; speedup 1.0000x reference)
//
#include <hip/hip_runtime.h>
#include <hip/hip_bf16.h>

#define NEG_SLOPE 0.2f
#define AS 136   // padded LDS row stride (bf16 elems): breaks 128-stride bank conflicts
#define CAPD 64  // per-wave LDS ex cache depth (edges per dst); overflow -> global EX2
#define L2E 1.44269504f
#define EPB 4096 // edges per binning chunk
#define TB  1024 // tail grid: 4 blocks/CU x 256 CU, co-residency guaranteed

typedef __bf16 bf16x8 __attribute__((ext_vector_type(8)));
typedef float  f32x4  __attribute__((ext_vector_type(4)));

__device__ __forceinline__ float b2f(__hip_bfloat16 v) { return __bfloat162float(v); }
__device__ __forceinline__ __hip_bfloat16 f2b(float v) { return __float2bfloat16(v); }
__device__ __forceinline__ float lo16(unsigned u) { return __uint_as_float(u << 16); }
__device__ __forceinline__ float hi16(unsigned u) { return __uint_as_float(u & 0xFFFF0000u); }

template<int CTRL>
__device__ __forceinline__ float dpp_add(float p) {
    int t = __builtin_amdgcn_update_dpp(0, __float_as_int(p), CTRL, 0xF, 0xF, true);
    return p + __int_as_float(t);
}

__device__ __forceinline__ float fexp2(float x) {
    float r;
    asm("v_exp_f32 %0, %1" : "=v"(r) : "v"(x));
    return r;
}

__device__ __forceinline__ int wild16(unsigned short w) {
    int e = (w >> 7) & 0xFF;
    return (e == 0 || e >= 0xC0) ? 1 : 0;
}

__device__ __forceinline__ void store_out(void* out, size_t idx, float v, int isF32) {
    if (isF32) ((float*)out)[idx] = v;
    else       ((__hip_bfloat16*)out)[idx] = f2b(v);
}

// device-scope grid barrier (co-resident grid only). RELEASE add emits L2
// writeback; ACQUIRE spin-load emits L2 invalidate -> cross-XCD visibility.
__device__ __forceinline__ void gridbar(int* bar, int nblk) {
    __syncthreads();
    if (threadIdx.x == 0) {
        __hip_atomic_fetch_add(bar, 1, __ATOMIC_RELEASE, __HIP_MEMORY_SCOPE_AGENT);
        while (__hip_atomic_load(bar, __ATOMIC_ACQUIRE, __HIP_MEMORY_SCOPE_AGENT) < nblk)
            __builtin_amdgcn_s_sleep(1);
    }
    __syncthreads();
}

#define NCVT 13
struct CvtTab {
    const void* src[NCVT];
    float*      dst[NCVT];
    int         n[NCVT];
    int         total;
};
struct WtTab { const void* src[5]; __hip_bfloat16* dst[5]; };

// ===== fused preprocessing: binA histogram | weight cvt+transpose | cvt =====
__global__ __launch_bounds__(1024) void k_pre(const int* __restrict__ ei, int E,
        int ET, int N, int shift, int nbkt, int b1, int* __restrict__ gcnt,
        CvtTab tab, WtTab wt, const unsigned short* __restrict__ det,
        int* __restrict__ FLAG, int* __restrict__ BAR) {
    __shared__ int shp[1024];
    __shared__ __hip_bfloat16 wst[1024];
    int t = threadIdx.x, b = blockIdx.x;
    if (b < b1) {                       // ---- binA ----
        if (t < 512) shp[t] = 0;
        __syncthreads();
        int e0 = b * EPB, e1 = min(e0 + EPB, ET);
        for (int e = e0 + t; e < e1; e += 1024) {
            int d = (e < E) ? ei[E + e] : (e - E);
            if ((unsigned)d < (unsigned)N) atomicAdd(&shp[d >> shift], 1);
        }
        __syncthreads();
        for (int i = t; i < nbkt; i += 1024) gcnt[(size_t)i * b1 + b] = shp[i];
        return;
    }
    // ---- dtype detection (same 1024 even samples as before) ----
    shp[t] = wild16(det[t * 2]);
    __syncthreads();
    for (int off = 512; off >= 1; off >>= 1) {
        if (t < off) shp[t] += shp[t + off];
        __syncthreads();
    }
    int isF32 = shp[0] > 128;
    int j = b - b1;
    if (j < 80) {                       // ---- weight cvt+transpose (LDS) ----
        if (j == 0 && t == 0) *FLAG = isF32;
        if (j == 0 && t < 8) BAR[t] = 0;       // reset grid barriers (per replay)
        int kl = t >> 7;                // local k row 0..7
        int m  = j >> 4;                // matrix index (16 blocks per matrix)
        int k0 = (j & 15) * 8;
        int k  = k0 + kl, c = t & 127;
        float v = isF32 ? ((const float*)wt.src[m])[k * 128 + c]
                        : b2f(((const __hip_bfloat16*)wt.src[m])[k * 128 + c]);
        wst[c * 8 + kl] = f2b(v);       // [c][kl] transposed tile
        __syncthreads();
        if (t < 128)                    // 16B contiguous store per output col c=t
            *((uint4*)(wt.dst[m] + t * 128 + k0)) = ((const uint4*)wst)[t];
    } else {                            // ---- small-tensor cvt ----
        int i = (j - 80) * 1024 + t;
        if (i >= tab.total) return;
        int seg = 0, rem = i;
        while (rem >= tab.n[seg]) { rem -= tab.n[seg]; ++seg; }
        float v = isF32 ? ((const float*)tab.src[seg])[rem]
                        : b2f(((const __hip_bfloat16*)tab.src[seg])[rem]);
        tab.dst[seg][rem] = v;
    }
}

// phase A of the offset scan: per-block exclusive scan of M contiguous counts
__global__ __launch_bounds__(256) void k_scanA(const int* __restrict__ cnt, int M,
                                               int* __restrict__ out, int* __restrict__ bsum) {
    __shared__ int sh[256];
    int t = threadIdx.x, i = blockIdx.x * 256 + t;
    int v = (i < M) ? cnt[i] : 0;
    sh[t] = v;
    __syncthreads();
    for (int off = 1; off < 256; off <<= 1) {
        int u = (t >= off) ? sh[t - off] : 0;
        __syncthreads();
        sh[t] += u;
        __syncthreads();
    }
    if (i < M) out[i] = sh[t] - v;                   // block-local exclusive
    if (t == 255) bsum[blockIdx.x] = sh[255];
}

// pass 1b: scatter packed (e, s|d_off<<20) into bucket-grouped staging.
__global__ __launch_bounds__(256) void k_binB(const int* __restrict__ ei, int E,
        int ET, int N, int shift, int nbkt, int b1, const int* __restrict__ offs,
        const int* __restrict__ bsum, int MB, int2* __restrict__ stg) {
    __shared__ int sh[256];
    __shared__ int sbex[1024];   // global-exclusive scan of bsum (MB <= 1024)
    __shared__ int base[512];
    int t = threadIdx.x, blk = blockIdx.x;
    int carry = 0;
    for (int bs = 0; bs < MB; bs += 256) {
        int idx = bs + t;
        int vv = (idx < MB) ? bsum[idx] : 0;
        sh[t] = vv;
        __syncthreads();
        for (int off = 1; off < 256; off <<= 1) {
            int u = (t >= off) ? sh[t - off] : 0;
            __syncthreads();
            sh[t] += u;
            __syncthreads();
        }
        if (idx < MB) sbex[idx] = carry + sh[t] - vv;
        carry += sh[255];
        __syncthreads();
    }
    for (int i = t; i < nbkt; i += 256) {
        int gi = i * b1 + blk;
        base[i] = offs[gi] + sbex[gi >> 8];
    }
    __syncthreads();
    int mask = (1 << shift) - 1;
    int e0 = blk * EPB, e1 = min(e0 + EPB, ET);
    for (int e = e0 + t; e < e1; e += 256) {
        int s, d;
        if (e < E) { s = ei[e]; d = ei[E + e]; } else { s = d = e - E; }
        if ((unsigned)d >= (unsigned)N) continue;
        int pos = atomicAdd(&base[d >> shift], 1);   // LDS atomic
        stg[pos] = make_int2(e, s | ((d & mask) << 20));
    }
}

// ===== FUSED: per-bucket fine CSR  ||  layer-1 encoder+dual GEMM ==========
__global__ __launch_bounds__(256) void k_csr_gemm(
        const int2* __restrict__ stg, const int* __restrict__ offs,
        const int* __restrict__ bsum, int MB, int N, int shift, int b1,
        int nbkt, int* __restrict__ rs, int2* __restrict__ pk,
        const void* __restrict__ x, const float* __restrict__ encW,
        const float* __restrict__ encb, const int* __restrict__ flag,
        const __hip_bfloat16* __restrict__ WLt, const float* __restrict__ bl,
        const __hip_bfloat16* __restrict__ WRt, const float* __restrict__ br,
        __hip_bfloat16* __restrict__ xl, __hip_bfloat16* __restrict__ xr) {
    __shared__ __align__(16) char smem[(64 + 128) * AS * 2];   // 52 KB union
    int t = threadIdx.x;
    if (blockIdx.x < nbkt) {
        // ------------------------- csr branch -------------------------
        int* off2 = (int*)smem;          // 512
        int* cnt2 = off2 + 512;          // 512
        int* part = cnt2 + 512;          // 256
        int* red  = part + 256;          // 256
        int bkt = blockIdx.x;
        int node0 = bkt << shift;
        int npb = 1 << shift;
        int mask = npb - 1;
        int nn = min(npb, N - node0);
        int i0 = bkt * b1, i1 = (bkt + 1) * b1;
        int c0 = i0 >> 8, c1 = i1 >> 8;
        int a0 = 0, a1 = 0, aT = 0;
        for (int bb = t; bb < MB; bb += 256) {
            int vb = bsum[bb];
            aT += vb;
            if (bb < c0) a0 += vb;
            if (bb < c1) a1 += vb;
        }
        red[t] = a0; __syncthreads();
        for (int off = 128; off >= 1; off >>= 1) { if (t < off) red[t] += red[t + off]; __syncthreads(); }
        int S0 = red[0]; __syncthreads();
        red[t] = a1; __syncthreads();
        for (int off = 128; off >= 1; off >>= 1) { if (t < off) red[t] += red[t + off]; __syncthreads(); }
        int S1 = red[0]; __syncthreads();
        red[t] = aT; __syncthreads();
        for (int off = 128; off >= 1; off >>= 1) { if (t < off) red[t] += red[t + off]; __syncthreads(); }
        int ST = red[0]; __syncthreads();
        int b0 = S0 + offs[i0];
        int bend = (bkt + 1 < nbkt) ? (S1 + offs[i1]) : ST;
        if (bkt == nbkt - 1 && t == 0) rs[N] = ST;
        int ec = bend - b0;
        for (int i = t; i < nn; i += 256) cnt2[i] = 0;
        __syncthreads();
        for (int i = t; i < ec; i += 256) {
            int2 es = stg[b0 + i];
            atomicAdd(&cnt2[(es.y >> 20) & mask], 1);
        }
        __syncthreads();
        int loc[2], sum = 0, base2 = t * 2;
#pragma unroll
        for (int k = 0; k < 2; ++k) {
            int idx = base2 + k;
            int v = (idx < nn) ? cnt2[idx] : 0;
            loc[k] = sum; sum += v;
        }
        part[t] = sum;
        __syncthreads();
        for (int off = 1; off < 256; off <<= 1) {
            int u = (t >= off) ? part[t - off] : 0;
            __syncthreads();
            part[t] += u;
            __syncthreads();
        }
        int pbase = part[t] - sum;
#pragma unroll
        for (int k = 0; k < 2; ++k) {
            int idx = base2 + k;
            if (idx < nn) {
                int p = b0 + pbase + loc[k];
                off2[idx] = p;
                rs[node0 + idx] = p;
            }
        }
        __syncthreads();
        for (int i = t; i < ec; i += 256) {
            int2 es = stg[b0 + i];
            int dof = (es.y >> 20) & mask;
            int pos = atomicAdd(&off2[dof], 1);      // LDS atomic
            pk[pos] = make_int2(es.x, es.y & 0xFFFFF);
        }
        return;
    }
    // ------------------------- gemm2enc branch -------------------------
    __hip_bfloat16* hA = (__hip_bfloat16*)smem;      // 64*AS
    __hip_bfloat16* wB = hA + 64 * AS;               // 128*AS
    float* encWs = (float*)wB;            // 2048 f32 (8 KB), aliased into wB
    float* xs    = encWs + 2048;          // 64*17 f32 (4.4 KB)
    int rbase = (blockIdx.x - nbkt) * 64;
    int isF32 = *flag;
    for (int i = t; i < 2048; i += 256) encWs[i] = encW[i];
    for (int i = t; i < 1024; i += 256) {
        int r = i >> 4, k = i & 15, gr = rbase + r;
        float v = 0.f;
        if (gr < N)
            v = isF32 ? ((const float*)x)[(size_t)gr * 16 + k]
                      : b2f(((const __hip_bfloat16*)x)[(size_t)gr * 16 + k]);
        xs[r * 17 + k] = v;
    }
    __syncthreads();
    {   // each thread: row r = t>>2, cols c = (t&3) + cc*4  (bank-spread)
        int r = t >> 2, q = t & 3;
        float xv[16];
#pragma unroll
        for (int k = 0; k < 16; ++k) xv[k] = xs[r * 17 + k];
#pragma unroll
        for (int cc = 0; cc < 32; ++cc) {
            int c = q + cc * 4;
            float acc = encb[c];
#pragma unroll
            for (int k = 0; k < 16; ++k) acc += xv[k] * encWs[k * 128 + c];
            hA[r * AS + c] = f2b(acc);
        }
    }
    int wave = t >> 6, lane = t & 63, l16 = lane & 15, kq = lane >> 4;
#pragma unroll
    for (int pass = 0; pass < 2; ++pass) {
        const __hip_bfloat16* Wt = pass ? WRt : WLt;
        const float* bias        = pass ? br  : bl;
        __hip_bfloat16* out      = pass ? xr  : xl;
        __syncthreads();                           // hA done / wB free
        for (int i = t; i < 2048; i += 256) {      // stage Wt (32 KB)
            int c = i >> 4, seg = i & 15;
            ((uint4*)(wB + c * AS))[seg] = ((const uint4*)(Wt + c * 128))[seg];
        }
        __syncthreads();
        f32x4 acc[8];
#pragma unroll
        for (int i = 0; i < 8; ++i) acc[i] = (f32x4){0.f, 0.f, 0.f, 0.f};
#pragma unroll
        for (int ks = 0; ks < 4; ++ks) {
            int kofs = ks * 32 + kq * 8;
            bf16x8 a = *(const bf16x8*)(hA + (wave * 16 + l16) * AS + kofs);
#pragma unroll
            for (int cb = 0; cb < 8; ++cb) {
                bf16x8 b = *(const bf16x8*)(wB + (cb * 16 + l16) * AS + kofs);
                acc[cb] = __builtin_amdgcn_mfma_f32_16x16x32_bf16(a, b, acc[cb], 0, 0, 0);
            }
        }
#pragma unroll
        for (int cb = 0; cb < 8; ++cb) {
            int c = cb * 16 + l16;
            float bc = bias[c];
#pragma unroll
            for (int i = 0; i < 4; ++i) {
                int r = rbase + wave * 16 + kq * 4 + i;
                if (r < N) out[(size_t)r * 128 + c] = f2b(acc[cb][i] + bc);
            }
        }
    }
}

// ---------- device bodies for the persistent tail kernel -------------------

// GAT for one dst n, executed by one wave; exsh = per-wave CAPD*4 floats.
__device__ __forceinline__ void gat_one(
        const __hip_bfloat16* __restrict__ xl, const __hip_bfloat16* __restrict__ xr,
        const int* __restrict__ rs, const int2* __restrict__ pk, int N,
        const float* __restrict__ att, const float* __restrict__ bo, int relu,
        float* __restrict__ EX2, void* __restrict__ alpha_out, size_t aoff,
        int isF32, __hip_bfloat16* __restrict__ hout, float* exsh, int n, int lane) {
    int h = lane >> 4, l16 = lane & 15, c0 = lane * 2;
    unsigned uxr = ((const unsigned*)(xr + (size_t)n * 128))[lane];
    float xr0 = lo16(uxr), xr1 = hi16(uxr);
    float a0 = att[c0] * L2E, a1 = att[c0 + 1] * L2E;
    float a06 = 0.6f * a0, a04 = 0.4f * a0;
    float a16 = 0.6f * a1, a14 = 0.4f * a1;
    int beg = __builtin_amdgcn_readfirstlane(rs[n]);
    int end = __builtin_amdgcn_readfirstlane(rs[n + 1]);
    const char* xlb = (const char*)xl;
    const int* pks = (const int*)pk;
    int lb = lane << 2;
    float den = 0.f, acc0 = 0.f, acc1 = 0.f;
    int r = beg;
    __builtin_amdgcn_s_setprio(1);

#define GAT_BATCH(W) { \
    unsigned u[W]; float p[W]; \
    _Pragma("unroll") \
    for (int j = 0; j < W; ++j) { \
        unsigned s = min((unsigned)(pks[((r + j) << 1) | 1] & 0xFFFFF), (unsigned)(N - 1)); \
        u[j] = *(const unsigned*)(xlb + ((size_t)s << 8) + lb); \
    } \
    _Pragma("unroll") \
    for (int j = 0; j < W; ++j) { \
        float v0 = lo16(u[j]) + xr0, v1 = hi16(u[j]) + xr1; \
        float tt = fmaf(fabsf(v0), a04, v0 * a06); \
        tt = fmaf(v1, a16, tt); \
        p[j] = fmaf(fabsf(v1), a14, tt); \
    } \
    _Pragma("unroll") \
    for (int j = 0; j < W; ++j) { \
        p[j] = dpp_add<0x121>(p[j]); \
        p[j] = dpp_add<0x122>(p[j]); \
        p[j] = dpp_add<0x124>(p[j]); \
        p[j] = dpp_add<0x128>(p[j]); \
        p[j] = fexp2(__builtin_amdgcn_fmed3f(p[j], -43.f, 43.f)); \
    } \
    if (l16 == 0) { \
        _Pragma("unroll") \
        for (int j = 0; j < W; ++j) { \
            int idx = r + j - beg; \
            if (idx < CAPD) exsh[idx * 4 + h] = p[j]; \
            else            EX2[(size_t)(r + j) * 4 + h] = p[j]; \
        } \
    } \
    _Pragma("unroll") \
    for (int j = 0; j < W; ++j) { \
        den  += p[j]; \
        acc0 = fmaf(p[j], lo16(u[j]), acc0); \
        acc1 = fmaf(p[j], hi16(u[j]), acc1); \
    } \
    r += W; }

    while (r + 8 <= end) GAT_BATCH(8)
    if (r + 4 <= end) GAT_BATCH(4)
    if (r + 2 <= end) GAT_BATCH(2)
    if (r < end) GAT_BATCH(1)
#undef GAT_BATCH
    __builtin_amdgcn_s_setprio(0);

    float invn = 1.f / fmaxf(den, 1e-30f);
    float v0 = acc0 * invn + bo[c0], v1 = acc1 * invn + bo[c0 + 1];
    if (relu) { v0 = fmaxf(v0, 0.f); v1 = fmaxf(v1, 0.f); }
    __hip_bfloat16 h0 = f2b(v0), h1 = f2b(v1);
    ushort2 st;
    st.x = *(unsigned short*)&h0;
    st.y = *(unsigned short*)&h1;
    ((ushort2*)(hout + (size_t)n * 128))[lane] = st;
    for (int r0 = beg; r0 < end; r0 += 16) {
        int rr = r0 + l16;
        if (rr < end) {
            int idx = rr - beg;
            float ex = (idx < CAPD) ? exsh[idx * 4 + h]
                                    : EX2[(size_t)rr * 4 + h];
            int e = pk[rr].x;
            store_out(alpha_out, aoff + (size_t)e * 4 + h, ex * invn, isF32);
        }
    }
}

// 64-row dual GEMM tile with HALVED wB staging (fits 40KB LDS budget):
// stage hA once; per pass, per 64-col half: stage wB-half, MFMA 4 col-blocks.
__device__ __forceinline__ void gemm_tile_h(
        const __hip_bfloat16* __restrict__ in,
        const __hip_bfloat16* __restrict__ WLt, const float* __restrict__ bl,
        const __hip_bfloat16* __restrict__ WRt, const float* __restrict__ br,
        int N, __hip_bfloat16* __restrict__ xl, __hip_bfloat16* __restrict__ xr,
        int tile, __hip_bfloat16* hA, __hip_bfloat16* wB) {
    int t = threadIdx.x, rbase = tile * 64;
    __syncthreads();                               // LDS free from prior use
    for (int i = t; i < 1024; i += 256) {
        int r = i >> 4, seg = i & 15;
        int gr = rbase + r;
        uint4 v = {0u, 0u, 0u, 0u};
        if (gr < N) v = ((const uint4*)(in + (size_t)gr * 128))[seg];
        ((uint4*)(hA + r * AS))[seg] = v;
    }
    int wave = t >> 6, lane = t & 63, l16 = lane & 15, kq = lane >> 4;
#pragma unroll
    for (int pass = 0; pass < 2; ++pass) {
        const __hip_bfloat16* Wt = pass ? WRt : WLt;
        const float* bias        = pass ? br  : bl;
        __hip_bfloat16* out      = pass ? xr  : xl;
        f32x4 acc[8];
#pragma unroll
        for (int i = 0; i < 8; ++i) acc[i] = (f32x4){0.f, 0.f, 0.f, 0.f};
#pragma unroll
        for (int half = 0; half < 2; ++half) {
            __syncthreads();
            for (int i = t; i < 1024; i += 256) {  // stage 64 cols (16 KB)
                int c = i >> 4, seg = i & 15;
                ((uint4*)(wB + c * AS))[seg] =
                    ((const uint4*)(Wt + (half * 64 + c) * 128))[seg];
            }
            __syncthreads();
#pragma unroll
            for (int ks = 0; ks < 4; ++ks) {
                int kofs = ks * 32 + kq * 8;
                bf16x8 a = *(const bf16x8*)(hA + (wave * 16 + l16) * AS + kofs);
#pragma unroll
                for (int cb = 0; cb < 4; ++cb) {
                    bf16x8 b = *(const bf16x8*)(wB + (cb * 16 + l16) * AS + kofs);
                    acc[half * 4 + cb] =
                        __builtin_amdgcn_mfma_f32_16x16x32_bf16(a, b, acc[half * 4 + cb], 0, 0, 0);
                }
            }
        }
#pragma unroll
        for (int q = 0; q < 8; ++q) {
            int c = q * 16 + l16;                  // == (q>>2)*64 + (q&3)*16 + l16
            float bc = bias[c];
#pragma unroll
            for (int i = 0; i < 4; ++i) {
                int r = rbase + wave * 16 + kq * 4 + i;
                if (r < N) out[(size_t)r * 128 + c] = f2b(acc[q][i] + bc);
            }
        }
    }
}

// MLP tile with halved wB staging; epilogue = relu()*W2 row-reduce + sigmoid.
__device__ __forceinline__ void mlp_tile_h(
        const __hip_bfloat16* __restrict__ h2, const __hip_bfloat16* __restrict__ W1t,
        const float* __restrict__ b1, const float* __restrict__ W2,
        const float* __restrict__ b2, int N, void* __restrict__ d_out,
        int isF32, int tile, __hip_bfloat16* hA, __hip_bfloat16* wB) {
    int t = threadIdx.x, rbase = tile * 64;
    __syncthreads();
    for (int i = t; i < 1024; i += 256) {
        int r = i >> 4, seg = i & 15;
        int gr = rbase + r;
        uint4 v = {0u, 0u, 0u, 0u};
        if (gr < N) v = ((const uint4*)(h2 + (size_t)gr * 128))[seg];
        ((uint4*)(hA + r * AS))[seg] = v;
    }
    int wave = t >> 6, lane = t & 63, l16 = lane & 15, kq = lane >> 4;
    f32x4 acc[8];
#pragma unroll
    for (int i = 0; i < 8; ++i) acc[i] = (f32x4){0.f, 0.f, 0.f, 0.f};
#pragma unroll
    for (int half = 0; half < 2; ++half) {
        __syncthreads();
        for (int i = t; i < 1024; i += 256) {
            int c = i >> 4, seg = i & 15;
            ((uint4*)(wB + c * AS))[seg] =
                ((const uint4*)(W1t + (half * 64 + c) * 128))[seg];
        }
        __syncthreads();
#pragma unroll
        for (int ks = 0; ks < 4; ++ks) {
            int kofs = ks * 32 + kq * 8;
            bf16x8 a = *(const bf16x8*)(hA + (wave * 16 + l16) * AS + kofs);
#pragma unroll
            for (int cb = 0; cb < 4; ++cb) {
                bf16x8 b = *(const bf16x8*)(wB + (cb * 16 + l16) * AS + kofs);
                acc[half * 4 + cb] =
                    __builtin_amdgcn_mfma_f32_16x16x32_bf16(a, b, acc[half * 4 + cb], 0, 0, 0);
            }
        }
    }
    float p[4] = {0.f, 0.f, 0.f, 0.f};
#pragma unroll
    for (int q = 0; q < 8; ++q) {
        int c = q * 16 + l16;
        float bb = b1[c], w = W2[c];
#pragma unroll
        for (int i = 0; i < 4; ++i) p[i] += fmaxf(acc[q][i] + bb, 0.f) * w;
    }
#pragma unroll
    for (int i = 0; i < 4; ++i) {
        p[i] += __shfl_xor(p[i], 8, 16);
        p[i] += __shfl_xor(p[i], 4, 16);
        p[i] += __shfl_xor(p[i], 2, 16);
        p[i] += __shfl_xor(p[i], 1, 16);
    }
    if (l16 == 0) {
        float bb = b2[0];
#pragma unroll
        for (int i = 0; i < 4; ++i) {
            int r = rbase + wave * 16 + kq * 4 + i;
            if (r < N)
                store_out(d_out, (size_t)r,
                          1.f / (1.f + __expf(-(p[i] + bb))), isF32);
        }
    }
}

// ===== persistent tail: {gat1 | gemm2 | gat2 | mlp} with 3 grid barriers ===
// __launch_bounds__(256,4): 4 waves/EU -> 4 blocks/CU guaranteed; grid = TB
// = 4 x 256 CU -> co-resident. LDS 34.8KB <= 40KB/block budget.
__global__ __launch_bounds__(256, 4) void k_tail(
        const __hip_bfloat16* __restrict__ XL, const __hip_bfloat16* __restrict__ XR,
        const int* __restrict__ rs, const int2* __restrict__ pk, int N, int gtiles,
        const float* __restrict__ att1, const float* __restrict__ bo1,
        const float* __restrict__ att2, const float* __restrict__ bo2,
        float* __restrict__ EX2, void* __restrict__ d_out,
        size_t a1_off, size_t a2_off, const int* __restrict__ flag,
        __hip_bfloat16* __restrict__ Hb,
        const __hip_bfloat16* __restrict__ W2Lt, const float* __restrict__ b2l,
        const __hip_bfloat16* __restrict__ W2Rt, const float* __restrict__ b2r,
        const __hip_bfloat16* __restrict__ MW1t, const float* __restrict__ mb1,
        const float* __restrict__ mW2, const float* __restrict__ mb2,
        int* __restrict__ BAR) {
    __shared__ __align__(16) char smem[64 * AS * 2 * 2];   // hA + wB (34.8 KB)
    __hip_bfloat16* hA = (__hip_bfloat16*)smem;
    __hip_bfloat16* wB = hA + 64 * AS;
    int t = threadIdx.x, wv = t >> 6, lane = t & 63;
    int isF32 = *flag;
    int gw = blockIdx.x * 4 + wv;                 // global wave id (0..4*TB)
    float* exsh = (float*)smem + wv * CAPD * 4;   // per-wave ex cache slice

    // ---- phase 1: GAT layer 1 (XL,XR -> Hb, alpha1) ----
    for (int n = gw; n < N; n += TB * 4)
        gat_one(XL, XR, rs, pk, N, att1, bo1, 1, EX2, d_out, a1_off, isF32,
                Hb, exsh, n, lane);
    gridbar(&BAR[0], TB);

    // ---- phase 2: layer-2 dual GEMM (Hb -> XL,XR) ----
    for (int tile = blockIdx.x; tile < gtiles; tile += TB)
        gemm_tile_h(Hb, W2Lt, b2l, W2Rt, b2r, N, (__hip_bfloat16*)XL,
                    (__hip_bfloat16*)XR, tile, hA, wB);
    gridbar(&BAR[1], TB);

    // ---- phase 3: GAT layer 2 (XL,XR -> Hb, alpha2) ----
    for (int n = gw; n < N; n += TB * 4)
        gat_one(XL, XR, rs, pk, N, att2, bo2, 0, EX2, d_out, a2_off, isF32,
                Hb, exsh, n, lane);
    gridbar(&BAR[2], TB);

    // ---- phase 4: MLP head (Hb -> probs) ----
    for (int tile = blockIdx.x; tile < gtiles; tile += TB)
        mlp_tile_h(Hb, MW1t, mb1, mW2, mb2, N, d_out, isF32, tile, hA, wB);
}

extern "C" void kernel_launch(void* const* d_in, const int* in_sizes, int n_in,
                              void* d_out, int out_size, void* d_ws, size_t ws_size,
                              hipStream_t stream) {
    const int* ei = (const int*)d_in[1];
    const int N  = in_sizes[0] / 16;
    const int E  = in_sizes[1] / 2;
    const int ET = E + N;

    // bucket geometry: <=512 buckets (128 nodes/bucket at N=50K)
    int shift = 7;
    while (((N + (1 << shift) - 1) >> shift) > 512) ++shift;
    const int nbkt = (N + (1 << shift) - 1) >> shift;
    const int B1   = (ET + EPB - 1) / EPB;
    const int M    = nbkt * B1;                 // scan length
    const int MB   = (M + 255) / 256;           // scan blocks (<=1024 assumed)

    // ---------------- workspace carve ------------------------------------
    float* P = (float*)d_ws;
    float* encW = P; P += 2048;  float* encb = P; P += 128;
    float* b1l  = P; P += 128;   float* b1r  = P; P += 128;
    float* att1 = P; P += 128;   float* bo1  = P; P += 128;
    float* b2l  = P; P += 128;   float* b2r  = P; P += 128;
    float* att2 = P; P += 128;   float* bo2  = P; P += 128;
    float* mb1  = P; P += 128;   float* mW2  = P; P += 128;
    float* mb2  = P; P += 4;
    int*  FLAG  = (int*)P; P += 4;
    int*  BAR   = (int*)P; P += 8;
    int*  RS    = (int*)P; P += N + 1;
    int*  GCNT  = (int*)P; P += M;
    int*  OFFS  = (int*)P; P += M;
    int*  BSUM  = (int*)P; P += MB;
    P = (float*)(((uintptr_t)P + 7) & ~(uintptr_t)7);     // 8B align
    int2* PK    = (int2*)P; P += (size_t)ET * 2;          // packed (e, src)
    float* EX2  = P; P += (size_t)ET * 4;
    // staging aliases EX2 (only live before the GAT kernels run):
    int2* STG   = (int2*)EX2;                             // ET packed records
    // 256-align the bf16 matrix region (256 B feature rows = 2 cache lines)
    P = (float*)(((uintptr_t)P + 255) & ~(uintptr_t)255);
    __hip_bfloat16* W1Lt = (__hip_bfloat16*)P;            // 5 x 128*128 bf16
    __hip_bfloat16* W1Rt = W1Lt + 16384;
    __hip_bfloat16* W2Lt = W1Rt + 16384;
    __hip_bfloat16* W2Rt = W2Lt + 16384;
    __hip_bfloat16* MW1t = W2Rt + 16384;
    __hip_bfloat16* Hb   = MW1t + 16384;                  // N*128 bf16 (256B-aligned)
    __hip_bfloat16* XL   = Hb + (size_t)N * 128;
    __hip_bfloat16* XR   = XL + (size_t)N * 128;

    // ---------------- fused preprocessing (1 launch) ----------------------
    CvtTab tab;
    const int srcIdx[NCVT] = {4, 5, 7, 9, 10, 11, 13, 15, 16, 17, 19, 20, 21};
    float* dsts[NCVT] = {encW, encb, b1l, b1r, att1, bo1, b2l, b2r, att2, bo2, mb1, mW2, mb2};
    const int ns[NCVT] = {2048, 128, 128, 128, 128, 128, 128, 128, 128, 128, 128, 128, 1};
    int tot = 0;
    for (int i = 0; i < NCVT; ++i) {
        tab.src[i] = d_in[srcIdx[i]];
        tab.dst[i] = dsts[i];
        tab.n[i] = ns[i];
        tot += ns[i];
    }
    tab.total = tot;
    WtTab wt;
    wt.src[0] = d_in[6];  wt.dst[0] = W1Lt;
    wt.src[1] = d_in[8];  wt.dst[1] = W1Rt;
    wt.src[2] = d_in[12]; wt.dst[2] = W2Lt;
    wt.src[3] = d_in[14]; wt.dst[3] = W2Rt;
    wt.src[4] = d_in[18]; wt.dst[4] = MW1t;
    const unsigned short* det = (const unsigned short*)d_in[4];  // enc_W raw
    const int preGrid = B1 + 80 + (tot + 1023) / 1024;
    k_pre<<<preGrid, 1024, 0, stream>>>(ei, E, ET, N, shift, nbkt, B1, GCNT,
                                        tab, wt, det, FLAG, BAR);

    // ---------------- CSR by dst + layer-1 GEMM (overlapped) ---------------
    const int gGrid = (N + 63) / 64;
    k_scanA<<<MB, 256, 0, stream>>>(GCNT, M, OFFS, BSUM);
    k_binB<<<B1, 256, 0, stream>>>(ei, E, ET, N, shift, nbkt, B1, OFFS, BSUM, MB, STG);
    k_csr_gemm<<<nbkt + gGrid, 256, 0, stream>>>(
        STG, OFFS, BSUM, MB, N, shift, B1, nbkt, RS, PK,
        d_in[0], encW, encb, FLAG, W1Lt, b1l, W1Rt, b1r, XL, XR);

    const size_t a1_off = (size_t)N;
    const size_t a2_off = (size_t)N + (size_t)ET * 4;

    // ---------------- persistent tail: gat1|gemm2|gat2|mlp -----------------
    k_tail<<<TB, 256, 0, stream>>>(XL, XR, RS, PK, N, gGrid,
                                   att1, bo1, att2, bo2, EX2, d_out,
                                   a1_off, a2_off, FLAG, Hb,
                                   W2Lt, b2l, W2Rt, b2r,
                                   MW1t, mb1, mW2, mb2, BAR);
}

// Round 12
// 354.543 us; speedup vs baseline: 2.4807x; 2.4807x over previous
//
#include <hip/hip_runtime.h>
#include <hip/hip_bf16.h>

#define NEG_SLOPE 0.2f
#define AS 136   // padded LDS row stride (bf16 elems): breaks 128-stride bank conflicts
#define CAPD 64  // per-wave LDS ex cache depth (edges per dst); overflow -> global EX2
#define L2E 1.44269504f
#define EPB 4096 // edges per binning chunk

typedef __bf16 bf16x8 __attribute__((ext_vector_type(8)));
typedef float  f32x4  __attribute__((ext_vector_type(4)));

__device__ __forceinline__ float b2f(__hip_bfloat16 v) { return __bfloat162float(v); }
__device__ __forceinline__ __hip_bfloat16 f2b(float v) { return __float2bfloat16(v); }
__device__ __forceinline__ float lo16(unsigned u) { return __uint_as_float(u << 16); }
__device__ __forceinline__ float hi16(unsigned u) { return __uint_as_float(u & 0xFFFF0000u); }

// DPP row_ror rotation-add: after ctrl 0x121,0x122,0x124,0x128 every lane of a
// 16-lane row holds the row sum. Pure VALU (no ds_bpermute, no lgkmcnt).
template<int CTRL>
__device__ __forceinline__ float dpp_add(float p) {
    int t = __builtin_amdgcn_update_dpp(0, __float_as_int(p), CTRL, 0xF, 0xF, true);
    return p + __int_as_float(t);
}

// raw v_exp_f32: 2^x in one instruction (log2e folded into att scale)
__device__ __forceinline__ float fexp2(float x) {
    float r;
    asm("v_exp_f32 %0, %1" : "=v"(r) : "v"(x));
    return r;
}

// wild-exponent test for one bf16-viewed ushort (even index of suspected fp32)
__device__ __forceinline__ int wild16(unsigned short w) {
    int e = (w >> 7) & 0xFF;
    return (e == 0 || e >= 0xC0) ? 1 : 0;
}

__device__ __forceinline__ void store_out(void* out, size_t idx, float v, int isF32) {
    if (isF32) ((float*)out)[idx] = v;
    else       ((__hip_bfloat16*)out)[idx] = f2b(v);
}

#define NCVT 13
struct CvtTab {
    const void* src[NCVT];
    float*      dst[NCVT];
    int         n[NCVT];
    int         total;
};
struct WtTab { const void* src[5]; __hip_bfloat16* dst[5]; };

// ===== fused preprocessing: binA histogram | weight cvt+transpose | cvt =====
__global__ __launch_bounds__(1024) void k_pre(const int* __restrict__ ei, int E,
        int ET, int N, int shift, int nbkt, int b1, int* __restrict__ gcnt,
        CvtTab tab, WtTab wt, const unsigned short* __restrict__ det,
        int* __restrict__ FLAG) {
    __shared__ int shp[1024];
    __shared__ __hip_bfloat16 wst[1024];
    int t = threadIdx.x, b = blockIdx.x;
    if (b < b1) {                       // ---- binA ----
        if (t < 512) shp[t] = 0;
        __syncthreads();
        int e0 = b * EPB, e1 = min(e0 + EPB, ET);
        for (int e = e0 + t; e < e1; e += 1024) {
            int d = (e < E) ? ei[E + e] : (e - E);
            if ((unsigned)d < (unsigned)N) atomicAdd(&shp[d >> shift], 1);
        }
        __syncthreads();
        for (int i = t; i < nbkt; i += 1024) gcnt[(size_t)i * b1 + b] = shp[i];
        return;
    }
    // ---- dtype detection (same 1024 even samples as before) ----
    shp[t] = wild16(det[t * 2]);
    __syncthreads();
    for (int off = 512; off >= 1; off >>= 1) {
        if (t < off) shp[t] += shp[t + off];
        __syncthreads();
    }
    int isF32 = shp[0] > 128;
    int j = b - b1;
    if (j < 80) {                       // ---- weight cvt+transpose (LDS) ----
        if (j == 0 && t == 0) *FLAG = isF32;
        int kl = t >> 7;                // local k row 0..7
        int m  = j >> 4;                // matrix index (16 blocks per matrix)
        int k0 = (j & 15) * 8;
        int k  = k0 + kl, c = t & 127;
        float v = isF32 ? ((const float*)wt.src[m])[k * 128 + c]
                        : b2f(((const __hip_bfloat16*)wt.src[m])[k * 128 + c]);
        wst[c * 8 + kl] = f2b(v);       // [c][kl] transposed tile
        __syncthreads();
        if (t < 128)                    // 16B contiguous store per output col c=t
            *((uint4*)(wt.dst[m] + t * 128 + k0)) = ((const uint4*)wst)[t];
    } else {                            // ---- small-tensor cvt ----
        int i = (j - 80) * 1024 + t;
        if (i >= tab.total) return;
        int seg = 0, rem = i;
        while (rem >= tab.n[seg]) { rem -= tab.n[seg]; ++seg; }
        float v = isF32 ? ((const float*)tab.src[seg])[rem]
                        : b2f(((const __hip_bfloat16*)tab.src[seg])[rem]);
        tab.dst[seg][rem] = v;
    }
}

// pass 1b: scatter packed (e, s|d_off<<20) into bucket-grouped staging.
// Self-contained offsets (scanA removed): each block row-scans GCNT for its
// own blk-prefix per bucket, LDS-scans the row totals for bucket bases.
// base[i] == round-10's offs[i*b1+blk]+sbex[..] exactly -> PK byte-identical.
// Block 0 publishes bb[] and rs[N].
__global__ __launch_bounds__(256) void k_binB(const int* __restrict__ ei, int E,
        int ET, int N, int shift, int nbkt, int b1, const int* __restrict__ gcnt,
        int2* __restrict__ stg, int* __restrict__ bb, int* __restrict__ rs) {
    __shared__ int rowpre[512];   // per-bucket prefix over blocks < blk
    __shared__ int rsum[512];     // per-bucket row totals -> exclusive bases
    __shared__ int base[512];
    __shared__ int part[256];
    int t = threadIdx.x, blk = blockIdx.x;
    for (int i = t; i < nbkt; i += 256) {
        const int* row = gcnt + (size_t)i * b1;
        int sum = 0, pre = 0;
        for (int bp = 0; bp < b1; ++bp) {
            int v = row[bp];
            if (bp == blk) pre = sum;
            sum += v;
        }
        rowpre[i] = pre;
        rsum[i] = sum;
    }
    __syncthreads();
    // exclusive scan of rsum[0..nbkt): thread t owns 2 consecutive elems
    int loc[2], sum2 = 0, base2 = t * 2;
#pragma unroll
    for (int k = 0; k < 2; ++k) {
        int idx = base2 + k;
        int v = (idx < nbkt) ? rsum[idx] : 0;
        loc[k] = sum2; sum2 += v;
    }
    part[t] = sum2;
    __syncthreads();
    for (int off = 1; off < 256; off <<= 1) {
        int u = (t >= off) ? part[t - off] : 0;
        __syncthreads();
        part[t] += u;
        __syncthreads();
    }
    int pbase = part[t] - sum2;
    int total = part[255];
#pragma unroll
    for (int k = 0; k < 2; ++k) {
        int idx = base2 + k;
        if (idx < nbkt) {
            int bbx = pbase + loc[k];
            base[idx] = bbx + rowpre[idx];
            if (blk == 0) bb[idx] = bbx;
        }
    }
    if (blk == 0 && t == 0) { bb[nbkt] = total; rs[N] = total; }
    __syncthreads();
    int mask = (1 << shift) - 1;
    int e0 = blk * EPB, e1 = min(e0 + EPB, ET);
    for (int e = e0 + t; e < e1; e += 256) {
        int s, d;
        if (e < E) { s = ei[e]; d = ei[E + e]; } else { s = d = e - E; }
        if ((unsigned)d >= (unsigned)N) continue;
        int pos = atomicAdd(&base[d >> shift], 1);   // LDS atomic
        stg[pos] = make_int2(e, s | ((d & mask) << 20));
    }
}

// ===== FUSED: per-bucket fine CSR  ||  layer-1 encoder+dual GEMM ==========
// blocks [0,nbkt): csr (memory/LDS-atomic bound), bases read from bb[]
// blocks [nbkt, nbkt+gGrid): gemm2enc (MFMA bound)
__global__ __launch_bounds__(256) void k_csr_gemm(
        // csr args
        const int2* __restrict__ stg, const int* __restrict__ bb,
        int N, int shift, int nbkt, int* __restrict__ rs, int2* __restrict__ pk,
        // gemm2enc args
        const void* __restrict__ x, const float* __restrict__ encW,
        const float* __restrict__ encb, const int* __restrict__ flag,
        const __hip_bfloat16* __restrict__ WLt, const float* __restrict__ bl,
        const __hip_bfloat16* __restrict__ WRt, const float* __restrict__ br,
        __hip_bfloat16* __restrict__ xl, __hip_bfloat16* __restrict__ xr) {
    __shared__ __align__(16) char smem[(64 + 128) * AS * 2];   // 52 KB union
    int t = threadIdx.x;
    if (blockIdx.x < nbkt) {
        // ------------------------- csr branch -------------------------
        int* off2 = (int*)smem;          // 512
        int* cnt2 = off2 + 512;          // 512
        int* part = cnt2 + 512;          // 256
        int bkt = blockIdx.x;
        int node0 = bkt << shift;
        int npb = 1 << shift;
        int mask = npb - 1;
        int nn = min(npb, N - node0);
        int b0 = bb[bkt], bend = bb[bkt + 1];
        int ec = bend - b0;
        for (int i = t; i < nn; i += 256) cnt2[i] = 0;
        __syncthreads();
        for (int i = t; i < ec; i += 256) {
            int2 es = stg[b0 + i];
            atomicAdd(&cnt2[(es.y >> 20) & mask], 1);
        }
        __syncthreads();
        int loc[2], sum = 0, base2 = t * 2;
#pragma unroll
        for (int k = 0; k < 2; ++k) {
            int idx = base2 + k;
            int v = (idx < nn) ? cnt2[idx] : 0;
            loc[k] = sum; sum += v;
        }
        part[t] = sum;
        __syncthreads();
        for (int off = 1; off < 256; off <<= 1) {
            int u = (t >= off) ? part[t - off] : 0;
            __syncthreads();
            part[t] += u;
            __syncthreads();
        }
        int pbase = part[t] - sum;
#pragma unroll
        for (int k = 0; k < 2; ++k) {
            int idx = base2 + k;
            if (idx < nn) {
                int p = b0 + pbase + loc[k];
                off2[idx] = p;
                rs[node0 + idx] = p;
            }
        }
        __syncthreads();
        for (int i = t; i < ec; i += 256) {
            int2 es = stg[b0 + i];
            int dof = (es.y >> 20) & mask;
            int pos = atomicAdd(&off2[dof], 1);      // LDS atomic
            pk[pos] = make_int2(es.x, es.y & 0xFFFFF);
        }
        return;
    }
    // ------------------------- gemm2enc branch -------------------------
    __hip_bfloat16* hA = (__hip_bfloat16*)smem;      // 64*AS
    __hip_bfloat16* wB = hA + 64 * AS;               // 128*AS
    float* encWs = (float*)wB;            // 2048 f32 (8 KB), aliased into wB
    float* xs    = encWs + 2048;          // 64*17 f32 (4.4 KB)
    int rbase = (blockIdx.x - nbkt) * 64;
    int isF32 = *flag;
    for (int i = t; i < 2048; i += 256) encWs[i] = encW[i];
    for (int i = t; i < 1024; i += 256) {
        int r = i >> 4, k = i & 15, gr = rbase + r;
        float v = 0.f;
        if (gr < N)
            v = isF32 ? ((const float*)x)[(size_t)gr * 16 + k]
                      : b2f(((const __hip_bfloat16*)x)[(size_t)gr * 16 + k]);
        xs[r * 17 + k] = v;
    }
    __syncthreads();
    {   // each thread: row r = t>>2, cols c = (t&3) + cc*4  (bank-spread)
        int r = t >> 2, q = t & 3;
        float xv[16];
#pragma unroll
        for (int k = 0; k < 16; ++k) xv[k] = xs[r * 17 + k];
#pragma unroll
        for (int cc = 0; cc < 32; ++cc) {
            int c = q + cc * 4;
            float acc = encb[c];
#pragma unroll
            for (int k = 0; k < 16; ++k) acc += xv[k] * encWs[k * 128 + c];
            hA[r * AS + c] = f2b(acc);
        }
    }
    int wave = t >> 6, lane = t & 63, l16 = lane & 15, kq = lane >> 4;
#pragma unroll
    for (int pass = 0; pass < 2; ++pass) {
        const __hip_bfloat16* Wt = pass ? WRt : WLt;
        const float* bias        = pass ? br  : bl;
        __hip_bfloat16* out      = pass ? xr  : xl;
        __syncthreads();                           // hA done / wB free
        for (int i = t; i < 2048; i += 256) {      // stage Wt (32 KB)
            int c = i >> 4, seg = i & 15;
            ((uint4*)(wB + c * AS))[seg] = ((const uint4*)(Wt + c * 128))[seg];
        }
        __syncthreads();
        f32x4 acc[8];
#pragma unroll
        for (int i = 0; i < 8; ++i) acc[i] = (f32x4){0.f, 0.f, 0.f, 0.f};
#pragma unroll
        for (int ks = 0; ks < 4; ++ks) {
            int kofs = ks * 32 + kq * 8;
            bf16x8 a = *(const bf16x8*)(hA + (wave * 16 + l16) * AS + kofs);
#pragma unroll
            for (int cb = 0; cb < 8; ++cb) {
                bf16x8 b = *(const bf16x8*)(wB + (cb * 16 + l16) * AS + kofs);
                acc[cb] = __builtin_amdgcn_mfma_f32_16x16x32_bf16(a, b, acc[cb], 0, 0, 0);
            }
        }
#pragma unroll
        for (int cb = 0; cb < 8; ++cb) {
            int c = cb * 16 + l16;
            float bc = bias[c];
#pragma unroll
            for (int i = 0; i < 4; ++i) {
                int r = rbase + wave * 16 + kq * 4 + i;
                if (r < N) out[(size_t)r * 128 + c] = f2b(acc[cb][i] + bc);
            }
        }
    }
}

// --- dual MFMA GEMM: stage hA once, loop over {Wl->xl, Wr->xr} -------------
__global__ __launch_bounds__(256) void k_gemm2_mfma(
        const __hip_bfloat16* __restrict__ in,
        const __hip_bfloat16* __restrict__ WLt, const float* __restrict__ bl,
        const __hip_bfloat16* __restrict__ WRt, const float* __restrict__ br,
        int N, __hip_bfloat16* __restrict__ xl, __hip_bfloat16* __restrict__ xr) {
    __shared__ __hip_bfloat16 hA[64 * AS];
    __shared__ __hip_bfloat16 wB[128 * AS];
    int t = threadIdx.x, rbase = blockIdx.x * 64;
    for (int i = t; i < 1024; i += 256) {          // stage 64 h rows (16 KB) ONCE
        int r = i >> 4, seg = i & 15;
        int gr = rbase + r;
        uint4 v = {0u, 0u, 0u, 0u};
        if (gr < N) v = ((const uint4*)(in + (size_t)gr * 128))[seg];
        ((uint4*)(hA + r * AS))[seg] = v;
    }
    int wave = t >> 6, lane = t & 63, l16 = lane & 15, kq = lane >> 4;
#pragma unroll
    for (int pass = 0; pass < 2; ++pass) {
        const __hip_bfloat16* Wt = pass ? WRt : WLt;
        const float* bias        = pass ? br  : bl;
        __hip_bfloat16* out      = pass ? xr  : xl;
        __syncthreads();
        for (int i = t; i < 2048; i += 256) {      // stage Wt (32 KB)
            int c = i >> 4, seg = i & 15;
            ((uint4*)(wB + c * AS))[seg] = ((const uint4*)(Wt + c * 128))[seg];
        }
        __syncthreads();
        f32x4 acc[8];
#pragma unroll
        for (int i = 0; i < 8; ++i) acc[i] = (f32x4){0.f, 0.f, 0.f, 0.f};
#pragma unroll
        for (int ks = 0; ks < 4; ++ks) {
            int kofs = ks * 32 + kq * 8;
            bf16x8 a = *(const bf16x8*)(hA + (wave * 16 + l16) * AS + kofs);
#pragma unroll
            for (int cb = 0; cb < 8; ++cb) {
                bf16x8 b = *(const bf16x8*)(wB + (cb * 16 + l16) * AS + kofs);
                acc[cb] = __builtin_amdgcn_mfma_f32_16x16x32_bf16(a, b, acc[cb], 0, 0, 0);
            }
        }
#pragma unroll
        for (int cb = 0; cb < 8; ++cb) {
            int c = cb * 16 + l16;
            float bc = bias[c];
#pragma unroll
            for (int i = 0; i < 4; ++i) {
                int r = rbase + wave * 16 + kq * 4 + i;
                if (r < N) out[(size_t)r * 128 + c] = f2b(acc[cb][i] + bc);
            }
        }
    }
}

// --------- MFMA MLP head: sigmoid(relu(h2@W1+b1)@W2 + b2), fused ----------
__global__ __launch_bounds__(256) void k_mlp_mfma(
        const __hip_bfloat16* __restrict__ h2, const __hip_bfloat16* __restrict__ W1t,
        const float* __restrict__ b1, const float* __restrict__ W2,
        const float* __restrict__ b2, int N,
        void* __restrict__ d_out, const int* __restrict__ flag) {
    __shared__ __hip_bfloat16 hA[64 * AS];
    __shared__ __hip_bfloat16 wB[128 * AS];
    int t = threadIdx.x, rbase = blockIdx.x * 64;
    for (int i = t; i < 2048; i += 256) {
        int c = i >> 4, seg = i & 15;
        ((uint4*)(wB + c * AS))[seg] = ((const uint4*)(W1t + c * 128))[seg];
    }
    for (int i = t; i < 1024; i += 256) {
        int r = i >> 4, seg = i & 15;
        int gr = rbase + r;
        uint4 v = {0u, 0u, 0u, 0u};
        if (gr < N) v = ((const uint4*)(h2 + (size_t)gr * 128))[seg];
        ((uint4*)(hA + r * AS))[seg] = v;
    }
    __syncthreads();
    int wave = t >> 6, lane = t & 63, l16 = lane & 15, kq = lane >> 4;
    f32x4 acc[8];
#pragma unroll
    for (int i = 0; i < 8; ++i) acc[i] = (f32x4){0.f, 0.f, 0.f, 0.f};
#pragma unroll
    for (int ks = 0; ks < 4; ++ks) {
        int kofs = ks * 32 + kq * 8;
        bf16x8 a = *(const bf16x8*)(hA + (wave * 16 + l16) * AS + kofs);
#pragma unroll
        for (int cb = 0; cb < 8; ++cb) {
            bf16x8 b = *(const bf16x8*)(wB + (cb * 16 + l16) * AS + kofs);
            acc[cb] = __builtin_amdgcn_mfma_f32_16x16x32_bf16(a, b, acc[cb], 0, 0, 0);
        }
    }
    float p[4] = {0.f, 0.f, 0.f, 0.f};
#pragma unroll
    for (int cb = 0; cb < 8; ++cb) {
        int c = cb * 16 + l16;
        float bb = b1[c], w = W2[c];
#pragma unroll
        for (int i = 0; i < 4; ++i) p[i] += fmaxf(acc[cb][i] + bb, 0.f) * w;
    }
#pragma unroll
    for (int i = 0; i < 4; ++i) {
        p[i] += __shfl_xor(p[i], 8, 16);
        p[i] += __shfl_xor(p[i], 4, 16);
        p[i] += __shfl_xor(p[i], 2, 16);
        p[i] += __shfl_xor(p[i], 1, 16);
    }
    if (l16 == 0) {
        int isF32 = *flag;
        float bb = b2[0];
#pragma unroll
        for (int i = 0; i < 4; ++i) {
            int r = rbase + wave * 16 + kq * 4 + i;
            if (r < N)
                store_out(d_out, (size_t)r,
                          1.f / (1.f + __expf(-(p[i] + bb))), isF32);
        }
    }
}

// ===== fused GAT edge pipeline: ONE dst per 64-thread block ===============
__global__ __launch_bounds__(64) void k_gat_fused(
        const __hip_bfloat16* __restrict__ xl,
        const __hip_bfloat16* __restrict__ xr,
        const int* __restrict__ rs, const int2* __restrict__ pk, int N,
        const float* __restrict__ att, const float* __restrict__ bo, int relu,
        float* __restrict__ EX2,
        void* __restrict__ alpha_out, size_t aoff, const int* __restrict__ flag,
        __hip_bfloat16* __restrict__ hout) {
    __shared__ float exsh[CAPD * 4];        // per-dst ex cache (1 KB)
    int lane = threadIdx.x;
    int n = blockIdx.x;
    if (n >= N) return;
    int h = lane >> 4, l16 = lane & 15, c0 = lane * 2;
    unsigned uxr = ((const unsigned*)(xr + (size_t)n * 128))[lane];
    float xr0 = lo16(uxr), xr1 = hi16(uxr);
    // leaky(v)*a = (0.6a)v + (0.4a)|v|  (exact for slope 0.2); log2e folded in
    float a0 = att[c0] * L2E, a1 = att[c0 + 1] * L2E;
    float a06 = 0.6f * a0, a04 = 0.4f * a0;
    float a16 = 0.6f * a1, a14 = 0.4f * a1;
    int beg = __builtin_amdgcn_readfirstlane(rs[n]);
    int end = __builtin_amdgcn_readfirstlane(rs[n + 1]);
    const char* xlb = (const char*)xl;
    const int* pks = (const int*)pk;        // scalar view: pks[2*r+1] = src
    int lb = lane << 2;
    float den = 0.f, acc0 = 0.f, acc1 = 0.f;
    int r = beg;
    __builtin_amdgcn_s_setprio(1);

#define GAT_BATCH(W) { \
    unsigned u[W]; float p[W]; \
    _Pragma("unroll") \
    for (int j = 0; j < W; ++j) { \
        unsigned s = min((unsigned)(pks[((r + j) << 1) | 1] & 0xFFFFF), (unsigned)(N - 1)); \
        u[j] = *(const unsigned*)(xlb + ((size_t)s << 8) + lb); \
    } \
    _Pragma("unroll") \
    for (int j = 0; j < W; ++j) { \
        float v0 = lo16(u[j]) + xr0, v1 = hi16(u[j]) + xr1; \
        float tt = fmaf(fabsf(v0), a04, v0 * a06); \
        tt = fmaf(v1, a16, tt); \
        p[j] = fmaf(fabsf(v1), a14, tt); \
    } \
    _Pragma("unroll") \
    for (int j = 0; j < W; ++j) { \
        p[j] = dpp_add<0x121>(p[j]); \
        p[j] = dpp_add<0x122>(p[j]); \
        p[j] = dpp_add<0x124>(p[j]); \
        p[j] = dpp_add<0x128>(p[j]); \
        p[j] = fexp2(__builtin_amdgcn_fmed3f(p[j], -43.f, 43.f)); \
    } \
    if (l16 == 0) { \
        _Pragma("unroll") \
        for (int j = 0; j < W; ++j) { \
            int idx = r + j - beg; \
            if (idx < CAPD) exsh[idx * 4 + h] = p[j]; \
            else            EX2[(size_t)(r + j) * 4 + h] = p[j]; \
        } \
    } \
    _Pragma("unroll") \
    for (int j = 0; j < W; ++j) { \
        den  += p[j]; \
        acc0 = fmaf(p[j], lo16(u[j]), acc0); \
        acc1 = fmaf(p[j], hi16(u[j]), acc1); \
    } \
    r += W; }

    while (r + 8 <= end) GAT_BATCH(8)
    if (r + 4 <= end) GAT_BATCH(4)
    if (r + 2 <= end) GAT_BATCH(2)
    if (r < end) GAT_BATCH(1)
#undef GAT_BATCH
    __builtin_amdgcn_s_setprio(0);

    float invn = 1.f / fmaxf(den, 1e-30f);
    float v0 = acc0 * invn + bo[c0], v1 = acc1 * invn + bo[c0 + 1];
    if (relu) { v0 = fmaxf(v0, 0.f); v1 = fmaxf(v1, 0.f); }
    __hip_bfloat16 h0 = f2b(v0), h1 = f2b(v1);
    ushort2 st;
    st.x = *(unsigned short*)&h0;
    st.y = *(unsigned short*)&h1;
    ((ushort2*)(hout + (size_t)n * 128))[lane] = st;
    // alpha outputs: 16 edges in parallel, lane (h,l16) handles (r0+l16, h)
    int isF32 = *flag;
    for (int r0 = beg; r0 < end; r0 += 16) {
        int rr = r0 + l16;
        if (rr < end) {
            int idx = rr - beg;
            float ex = (idx < CAPD) ? exsh[idx * 4 + h]
                                    : EX2[(size_t)rr * 4 + h];
            int e = pk[rr].x;
            store_out(alpha_out, aoff + (size_t)e * 4 + h, ex * invn, isF32);
        }
    }
}

extern "C" void kernel_launch(void* const* d_in, const int* in_sizes, int n_in,
                              void* d_out, int out_size, void* d_ws, size_t ws_size,
                              hipStream_t stream) {
    const int* ei = (const int*)d_in[1];
    const int N  = in_sizes[0] / 16;
    const int E  = in_sizes[1] / 2;
    const int ET = E + N;

    // bucket geometry: <=512 buckets (128 nodes/bucket at N=50K)
    int shift = 7;
    while (((N + (1 << shift) - 1) >> shift) > 512) ++shift;
    const int nbkt = (N + (1 << shift) - 1) >> shift;
    const int B1   = (ET + EPB - 1) / EPB;
    const int M    = nbkt * B1;

    // ---------------- workspace carve ------------------------------------
    float* P = (float*)d_ws;
    float* encW = P; P += 2048;  float* encb = P; P += 128;
    float* b1l  = P; P += 128;   float* b1r  = P; P += 128;
    float* att1 = P; P += 128;   float* bo1  = P; P += 128;
    float* b2l  = P; P += 128;   float* b2r  = P; P += 128;
    float* att2 = P; P += 128;   float* bo2  = P; P += 128;
    float* mb1  = P; P += 128;   float* mW2  = P; P += 128;
    float* mb2  = P; P += 4;
    int*  FLAG  = (int*)P; P += 4;
    int*  RS    = (int*)P; P += N + 1;
    int*  BB    = (int*)P; P += nbkt + 1;
    int*  GCNT  = (int*)P; P += M;
    P = (float*)(((uintptr_t)P + 7) & ~(uintptr_t)7);     // 8B align
    int2* PK    = (int2*)P; P += (size_t)ET * 2;          // packed (e, src)
    float* EX2  = P; P += (size_t)ET * 4;
    // staging aliases EX2 (only live before the GAT kernels run):
    int2* STG   = (int2*)EX2;                             // ET packed records
    // 256-align the bf16 matrix region (256 B feature rows = 2 cache lines)
    P = (float*)(((uintptr_t)P + 255) & ~(uintptr_t)255);
    __hip_bfloat16* W1Lt = (__hip_bfloat16*)P;            // 5 x 128*128 bf16
    __hip_bfloat16* W1Rt = W1Lt + 16384;
    __hip_bfloat16* W2Lt = W1Rt + 16384;
    __hip_bfloat16* W2Rt = W2Lt + 16384;
    __hip_bfloat16* MW1t = W2Rt + 16384;
    __hip_bfloat16* Hb   = MW1t + 16384;                  // N*128 bf16 (256B-aligned)
    __hip_bfloat16* XL   = Hb + (size_t)N * 128;
    __hip_bfloat16* XR   = XL + (size_t)N * 128;

    // ---------------- fused preprocessing (1 launch) ----------------------
    CvtTab tab;
    const int srcIdx[NCVT] = {4, 5, 7, 9, 10, 11, 13, 15, 16, 17, 19, 20, 21};
    float* dsts[NCVT] = {encW, encb, b1l, b1r, att1, bo1, b2l, b2r, att2, bo2, mb1, mW2, mb2};
    const int ns[NCVT] = {2048, 128, 128, 128, 128, 128, 128, 128, 128, 128, 128, 128, 1};
    int tot = 0;
    for (int i = 0; i < NCVT; ++i) {
        tab.src[i] = d_in[srcIdx[i]];
        tab.dst[i] = dsts[i];
        tab.n[i] = ns[i];
        tot += ns[i];
    }
    tab.total = tot;
    WtTab wt;
    wt.src[0] = d_in[6];  wt.dst[0] = W1Lt;
    wt.src[1] = d_in[8];  wt.dst[1] = W1Rt;
    wt.src[2] = d_in[12]; wt.dst[2] = W2Lt;
    wt.src[3] = d_in[14]; wt.dst[3] = W2Rt;
    wt.src[4] = d_in[18]; wt.dst[4] = MW1t;
    const unsigned short* det = (const unsigned short*)d_in[4];  // enc_W raw
    const int preGrid = B1 + 80 + (tot + 1023) / 1024;
    k_pre<<<preGrid, 1024, 0, stream>>>(ei, E, ET, N, shift, nbkt, B1, GCNT,
                                        tab, wt, det, FLAG);

    // ---------------- CSR by dst + layer-1 GEMM (overlapped) ---------------
    const int gGrid = (N + 63) / 64;
    k_binB<<<B1, 256, 0, stream>>>(ei, E, ET, N, shift, nbkt, B1, GCNT, STG, BB, RS);
    k_csr_gemm<<<nbkt + gGrid, 256, 0, stream>>>(
        STG, BB, N, shift, nbkt, RS, PK,
        d_in[0], encW, encb, FLAG, W1Lt, b1l, W1Rt, b1r, XL, XR);

    const size_t a1_off = (size_t)N;
    const size_t a2_off = (size_t)N + (size_t)ET * 4;

    // ---- GAT layer 1 ----
    k_gat_fused<<<N, 64, 0, stream>>>(XL, XR, RS, PK, N, att1, bo1, 1,
                                      EX2, d_out, a1_off, FLAG, Hb);

    // ---- GAT layer 2 ----
    k_gemm2_mfma<<<gGrid, 256, 0, stream>>>(Hb, W2Lt, b2l, W2Rt, b2r, N, XL, XR);
    k_gat_fused<<<N, 64, 0, stream>>>(XL, XR, RS, PK, N, att2, bo2, 0,
                                      EX2, d_out, a2_off, FLAG, Hb);

    k_mlp_mfma<<<gGrid, 256, 0, stream>>>(Hb, MW1t, mb1, mW2, mb2, N, d_out, FLAG);
}

// Round 13
// 300.871 us; speedup vs baseline: 2.9232x; 1.1784x over previous
//
#include <hip/hip_runtime.h>
#include <hip/hip_bf16.h>

#define NEG_SLOPE 0.2f
#define AS 136   // padded LDS row stride (bf16 elems): breaks 128-stride bank conflicts
#define CAPD 64  // per-wave LDS ex cache depth (edges per dst); overflow -> global EX2
#define L2E 1.44269504f
#define EPB 4096 // edges per binning chunk

typedef __bf16 bf16x8 __attribute__((ext_vector_type(8)));
typedef float  f32x4  __attribute__((ext_vector_type(4)));

__device__ __forceinline__ float b2f(__hip_bfloat16 v) { return __bfloat162float(v); }
__device__ __forceinline__ __hip_bfloat16 f2b(float v) { return __float2bfloat16(v); }
__device__ __forceinline__ float lo16(unsigned u) { return __uint_as_float(u << 16); }
__device__ __forceinline__ float hi16(unsigned u) { return __uint_as_float(u & 0xFFFF0000u); }

// DPP row_ror rotation-add: after ctrl 0x121,0x122,0x124,0x128 every lane of a
// 16-lane row holds the row sum. Pure VALU (no ds_bpermute, no lgkmcnt).
template<int CTRL>
__device__ __forceinline__ float dpp_add(float p) {
    int t = __builtin_amdgcn_update_dpp(0, __float_as_int(p), CTRL, 0xF, 0xF, true);
    return p + __int_as_float(t);
}

// raw v_exp_f32: 2^x in one instruction (log2e folded into att scale)
__device__ __forceinline__ float fexp2(float x) {
    float r;
    asm("v_exp_f32 %0, %1" : "=v"(r) : "v"(x));
    return r;
}

// wild-exponent test for one bf16-viewed ushort (even index of suspected fp32)
__device__ __forceinline__ int wild16(unsigned short w) {
    int e = (w >> 7) & 0xFF;
    return (e == 0 || e >= 0xC0) ? 1 : 0;
}

__device__ __forceinline__ void store_out(void* out, size_t idx, float v, int isF32) {
    if (isF32) ((float*)out)[idx] = v;
    else       ((__hip_bfloat16*)out)[idx] = f2b(v);
}

#define NCVT 13
struct CvtTab {
    const void* src[NCVT];
    float*      dst[NCVT];
    int         n[NCVT];
    int         total;
};
struct WtTab { const void* src[5]; __hip_bfloat16* dst[5]; };

// ===== fused preprocessing: binA histogram | weight cvt+transpose | cvt =====
__global__ __launch_bounds__(1024) void k_pre(const int* __restrict__ ei, int E,
        int ET, int N, int shift, int nbkt, int b1, int* __restrict__ gcnt,
        CvtTab tab, WtTab wt, const unsigned short* __restrict__ det,
        int* __restrict__ FLAG) {
    __shared__ int shp[1024];
    __shared__ __hip_bfloat16 wst[1024];
    int t = threadIdx.x, b = blockIdx.x;
    if (b < b1) {                       // ---- binA ----
        if (t < 512) shp[t] = 0;
        __syncthreads();
        int e0 = b * EPB, e1 = min(e0 + EPB, ET);
        for (int e = e0 + t; e < e1; e += 1024) {
            int d = (e < E) ? ei[E + e] : (e - E);
            if ((unsigned)d < (unsigned)N) atomicAdd(&shp[d >> shift], 1);
        }
        __syncthreads();
        for (int i = t; i < nbkt; i += 1024) gcnt[(size_t)i * b1 + b] = shp[i];
        return;
    }
    // ---- dtype detection (same 1024 even samples as before) ----
    shp[t] = wild16(det[t * 2]);
    __syncthreads();
    for (int off = 512; off >= 1; off >>= 1) {
        if (t < off) shp[t] += shp[t + off];
        __syncthreads();
    }
    int isF32 = shp[0] > 128;
    int j = b - b1;
    if (j < 80) {                       // ---- weight cvt+transpose (LDS) ----
        if (j == 0 && t == 0) *FLAG = isF32;
        int kl = t >> 7;                // local k row 0..7
        int m  = j >> 4;                // matrix index (16 blocks per matrix)
        int k0 = (j & 15) * 8;
        int k  = k0 + kl, c = t & 127;
        float v = isF32 ? ((const float*)wt.src[m])[k * 128 + c]
                        : b2f(((const __hip_bfloat16*)wt.src[m])[k * 128 + c]);
        wst[c * 8 + kl] = f2b(v);       // [c][kl] transposed tile
        __syncthreads();
        if (t < 128)                    // 16B contiguous store per output col c=t
            *((uint4*)(wt.dst[m] + t * 128 + k0)) = ((const uint4*)wst)[t];
    } else {                            // ---- small-tensor cvt ----
        int i = (j - 80) * 1024 + t;
        if (i >= tab.total) return;
        int seg = 0, rem = i;
        while (rem >= tab.n[seg]) { rem -= tab.n[seg]; ++seg; }
        float v = isF32 ? ((const float*)tab.src[seg])[rem]
                        : b2f(((const __hip_bfloat16*)tab.src[seg])[rem]);
        tab.dst[seg][rem] = v;
    }
}

// phase A of the offset scan: per-block exclusive scan of M contiguous counts
__global__ __launch_bounds__(256) void k_scanA(const int* __restrict__ cnt, int M,
                                               int* __restrict__ out, int* __restrict__ bsum) {
    __shared__ int sh[256];
    int t = threadIdx.x, i = blockIdx.x * 256 + t;
    int v = (i < M) ? cnt[i] : 0;
    sh[t] = v;
    __syncthreads();
    for (int off = 1; off < 256; off <<= 1) {
        int u = (t >= off) ? sh[t - off] : 0;
        __syncthreads();
        sh[t] += u;
        __syncthreads();
    }
    if (i < M) out[i] = sh[t] - v;                   // block-local exclusive
    if (t == 255) bsum[blockIdx.x] = sh[255];
}

// pass 1b: scatter packed (e, s|d_off<<20) into bucket-grouped staging.
// 256 threads (256-edge ordering window preserved); scans raw block-sums in
// LDS itself (MB small) to globalize the scanA-local offsets.
__global__ __launch_bounds__(256) void k_binB(const int* __restrict__ ei, int E,
        int ET, int N, int shift, int nbkt, int b1, const int* __restrict__ offs,
        const int* __restrict__ bsum, int MB, int2* __restrict__ stg) {
    __shared__ int sh[256];
    __shared__ int sbex[1024];   // global-exclusive scan of bsum (MB <= 1024)
    __shared__ int base[512];
    int t = threadIdx.x, blk = blockIdx.x;
    int carry = 0;
    for (int bs = 0; bs < MB; bs += 256) {
        int idx = bs + t;
        int vv = (idx < MB) ? bsum[idx] : 0;
        sh[t] = vv;
        __syncthreads();
        for (int off = 1; off < 256; off <<= 1) {
            int u = (t >= off) ? sh[t - off] : 0;
            __syncthreads();
            sh[t] += u;
            __syncthreads();
        }
        if (idx < MB) sbex[idx] = carry + sh[t] - vv;
        carry += sh[255];
        __syncthreads();
    }
    for (int i = t; i < nbkt; i += 256) {
        int gi = i * b1 + blk;
        base[i] = offs[gi] + sbex[gi >> 8];
    }
    __syncthreads();
    int mask = (1 << shift) - 1;
    int e0 = blk * EPB, e1 = min(e0 + EPB, ET);
    for (int e = e0 + t; e < e1; e += 256) {
        int s, d;
        if (e < E) { s = ei[e]; d = ei[E + e]; } else { s = d = e - E; }
        if ((unsigned)d >= (unsigned)N) continue;
        int pos = atomicAdd(&base[d >> shift], 1);   // LDS atomic
        stg[pos] = make_int2(e, s | ((d & mask) << 20));
    }
}

// ===== FUSED: per-bucket fine CSR  ||  layer-1 encoder+dual GEMM ==========
// blocks [0,nbkt): csr (memory/LDS-atomic bound)
// blocks [nbkt, nbkt+gGrid): gemm2enc (MFMA bound)
__global__ __launch_bounds__(256) void k_csr_gemm(
        // csr args
        const int2* __restrict__ stg, const int* __restrict__ offs,
        const int* __restrict__ bsum, int MB, int N, int shift, int b1,
        int nbkt, int* __restrict__ rs, int2* __restrict__ pk,
        // gemm2enc args
        const void* __restrict__ x, const float* __restrict__ encW,
        const float* __restrict__ encb, const int* __restrict__ flag,
        const __hip_bfloat16* __restrict__ WLt, const float* __restrict__ bl,
        const __hip_bfloat16* __restrict__ WRt, const float* __restrict__ br,
        __hip_bfloat16* __restrict__ xl, __hip_bfloat16* __restrict__ xr) {
    __shared__ __align__(16) char smem[(64 + 128) * AS * 2];   // 52 KB union
    int t = threadIdx.x;
    if (blockIdx.x < nbkt) {
        // ------------------------- csr branch -------------------------
        int* off2 = (int*)smem;          // 512
        int* cnt2 = off2 + 512;          // 512
        int* part = cnt2 + 512;          // 256
        int* red  = part + 256;          // 256
        int bkt = blockIdx.x;
        int node0 = bkt << shift;
        int npb = 1 << shift;
        int mask = npb - 1;
        int nn = min(npb, N - node0);
        int i0 = bkt * b1, i1 = (bkt + 1) * b1;
        int c0 = i0 >> 8, c1 = i1 >> 8;
        int a0 = 0, a1 = 0, aT = 0;
        for (int bb = t; bb < MB; bb += 256) {
            int vb = bsum[bb];
            aT += vb;
            if (bb < c0) a0 += vb;
            if (bb < c1) a1 += vb;
        }
        red[t] = a0; __syncthreads();
        for (int off = 128; off >= 1; off >>= 1) { if (t < off) red[t] += red[t + off]; __syncthreads(); }
        int S0 = red[0]; __syncthreads();
        red[t] = a1; __syncthreads();
        for (int off = 128; off >= 1; off >>= 1) { if (t < off) red[t] += red[t + off]; __syncthreads(); }
        int S1 = red[0]; __syncthreads();
        red[t] = aT; __syncthreads();
        for (int off = 128; off >= 1; off >>= 1) { if (t < off) red[t] += red[t + off]; __syncthreads(); }
        int ST = red[0]; __syncthreads();
        int b0 = S0 + offs[i0];
        int bend = (bkt + 1 < nbkt) ? (S1 + offs[i1]) : ST;
        if (bkt == nbkt - 1 && t == 0) rs[N] = ST;
        int ec = bend - b0;
        for (int i = t; i < nn; i += 256) cnt2[i] = 0;
        __syncthreads();
        for (int i = t; i < ec; i += 256) {
            int2 es = stg[b0 + i];
            atomicAdd(&cnt2[(es.y >> 20) & mask], 1);
        }
        __syncthreads();
        int loc[2], sum = 0, base2 = t * 2;
#pragma unroll
        for (int k = 0; k < 2; ++k) {
            int idx = base2 + k;
            int v = (idx < nn) ? cnt2[idx] : 0;
            loc[k] = sum; sum += v;
        }
        part[t] = sum;
        __syncthreads();
        for (int off = 1; off < 256; off <<= 1) {
            int u = (t >= off) ? part[t - off] : 0;
            __syncthreads();
            part[t] += u;
            __syncthreads();
        }
        int pbase = part[t] - sum;
#pragma unroll
        for (int k = 0; k < 2; ++k) {
            int idx = base2 + k;
            if (idx < nn) {
                int p = b0 + pbase + loc[k];
                off2[idx] = p;
                rs[node0 + idx] = p;
            }
        }
        __syncthreads();
        for (int i = t; i < ec; i += 256) {
            int2 es = stg[b0 + i];
            int dof = (es.y >> 20) & mask;
            int pos = atomicAdd(&off2[dof], 1);      // LDS atomic
            pk[pos] = make_int2(es.x, es.y & 0xFFFFF);
        }
        return;
    }
    // ------------------------- gemm2enc branch -------------------------
    __hip_bfloat16* hA = (__hip_bfloat16*)smem;      // 64*AS
    __hip_bfloat16* wB = hA + 64 * AS;               // 128*AS
    float* encWs = (float*)wB;            // 2048 f32 (8 KB), aliased into wB
    float* xs    = encWs + 2048;          // 64*17 f32 (4.4 KB)
    int rbase = (blockIdx.x - nbkt) * 64;
    int isF32 = *flag;
    for (int i = t; i < 2048; i += 256) encWs[i] = encW[i];
    for (int i = t; i < 1024; i += 256) {
        int r = i >> 4, k = i & 15, gr = rbase + r;
        float v = 0.f;
        if (gr < N)
            v = isF32 ? ((const float*)x)[(size_t)gr * 16 + k]
                      : b2f(((const __hip_bfloat16*)x)[(size_t)gr * 16 + k]);
        xs[r * 17 + k] = v;
    }
    __syncthreads();
    {   // each thread: row r = t>>2, cols c = (t&3) + cc*4  (bank-spread)
        int r = t >> 2, q = t & 3;
        float xv[16];
#pragma unroll
        for (int k = 0; k < 16; ++k) xv[k] = xs[r * 17 + k];
#pragma unroll
        for (int cc = 0; cc < 32; ++cc) {
            int c = q + cc * 4;
            float acc = encb[c];
#pragma unroll
            for (int k = 0; k < 16; ++k) acc += xv[k] * encWs[k * 128 + c];
            hA[r * AS + c] = f2b(acc);
        }
    }
    int wave = t >> 6, lane = t & 63, l16 = lane & 15, kq = lane >> 4;
#pragma unroll
    for (int pass = 0; pass < 2; ++pass) {
        const __hip_bfloat16* Wt = pass ? WRt : WLt;
        const float* bias        = pass ? br  : bl;
        __hip_bfloat16* out      = pass ? xr  : xl;
        __syncthreads();                           // hA done / wB free
        for (int i = t; i < 2048; i += 256) {      // stage Wt (32 KB)
            int c = i >> 4, seg = i & 15;
            ((uint4*)(wB + c * AS))[seg] = ((const uint4*)(Wt + c * 128))[seg];
        }
        __syncthreads();
        f32x4 acc[8];
#pragma unroll
        for (int i = 0; i < 8; ++i) acc[i] = (f32x4){0.f, 0.f, 0.f, 0.f};
#pragma unroll
        for (int ks = 0; ks < 4; ++ks) {
            int kofs = ks * 32 + kq * 8;
            bf16x8 a = *(const bf16x8*)(hA + (wave * 16 + l16) * AS + kofs);
#pragma unroll
            for (int cb = 0; cb < 8; ++cb) {
                bf16x8 b = *(const bf16x8*)(wB + (cb * 16 + l16) * AS + kofs);
                acc[cb] = __builtin_amdgcn_mfma_f32_16x16x32_bf16(a, b, acc[cb], 0, 0, 0);
            }
        }
#pragma unroll
        for (int cb = 0; cb < 8; ++cb) {
            int c = cb * 16 + l16;
            float bc = bias[c];
#pragma unroll
            for (int i = 0; i < 4; ++i) {
                int r = rbase + wave * 16 + kq * 4 + i;
                if (r < N) out[(size_t)r * 128 + c] = f2b(acc[cb][i] + bc);
            }
        }
    }
}

// --- dual MFMA GEMM: stage hA once, loop over {Wl->xl, Wr->xr} -------------
__global__ __launch_bounds__(256) void k_gemm2_mfma(
        const __hip_bfloat16* __restrict__ in,
        const __hip_bfloat16* __restrict__ WLt, const float* __restrict__ bl,
        const __hip_bfloat16* __restrict__ WRt, const float* __restrict__ br,
        int N, __hip_bfloat16* __restrict__ xl, __hip_bfloat16* __restrict__ xr) {
    __shared__ __hip_bfloat16 hA[64 * AS];
    __shared__ __hip_bfloat16 wB[128 * AS];
    int t = threadIdx.x, rbase = blockIdx.x * 64;
    for (int i = t; i < 1024; i += 256) {          // stage 64 h rows (16 KB) ONCE
        int r = i >> 4, seg = i & 15;
        int gr = rbase + r;
        uint4 v = {0u, 0u, 0u, 0u};
        if (gr < N) v = ((const uint4*)(in + (size_t)gr * 128))[seg];
        ((uint4*)(hA + r * AS))[seg] = v;
    }
    int wave = t >> 6, lane = t & 63, l16 = lane & 15, kq = lane >> 4;
#pragma unroll
    for (int pass = 0; pass < 2; ++pass) {
        const __hip_bfloat16* Wt = pass ? WRt : WLt;
        const float* bias        = pass ? br  : bl;
        __hip_bfloat16* out      = pass ? xr  : xl;
        __syncthreads();
        for (int i = t; i < 2048; i += 256) {      // stage Wt (32 KB)
            int c = i >> 4, seg = i & 15;
            ((uint4*)(wB + c * AS))[seg] = ((const uint4*)(Wt + c * 128))[seg];
        }
        __syncthreads();
        f32x4 acc[8];
#pragma unroll
        for (int i = 0; i < 8; ++i) acc[i] = (f32x4){0.f, 0.f, 0.f, 0.f};
#pragma unroll
        for (int ks = 0; ks < 4; ++ks) {
            int kofs = ks * 32 + kq * 8;
            bf16x8 a = *(const bf16x8*)(hA + (wave * 16 + l16) * AS + kofs);
#pragma unroll
            for (int cb = 0; cb < 8; ++cb) {
                bf16x8 b = *(const bf16x8*)(wB + (cb * 16 + l16) * AS + kofs);
                acc[cb] = __builtin_amdgcn_mfma_f32_16x16x32_bf16(a, b, acc[cb], 0, 0, 0);
            }
        }
#pragma unroll
        for (int cb = 0; cb < 8; ++cb) {
            int c = cb * 16 + l16;
            float bc = bias[c];
#pragma unroll
            for (int i = 0; i < 4; ++i) {
                int r = rbase + wave * 16 + kq * 4 + i;
                if (r < N) out[(size_t)r * 128 + c] = f2b(acc[cb][i] + bc);
            }
        }
    }
}

// --------- MFMA MLP head: sigmoid(relu(h2@W1+b1)@W2 + b2), fused ----------
__global__ __launch_bounds__(256) void k_mlp_mfma(
        const __hip_bfloat16* __restrict__ h2, const __hip_bfloat16* __restrict__ W1t,
        const float* __restrict__ b1, const float* __restrict__ W2,
        const float* __restrict__ b2, int N,
        void* __restrict__ d_out, const int* __restrict__ flag) {
    __shared__ __hip_bfloat16 hA[64 * AS];
    __shared__ __hip_bfloat16 wB[128 * AS];
    int t = threadIdx.x, rbase = blockIdx.x * 64;
    for (int i = t; i < 2048; i += 256) {
        int c = i >> 4, seg = i & 15;
        ((uint4*)(wB + c * AS))[seg] = ((const uint4*)(W1t + c * 128))[seg];
    }
    for (int i = t; i < 1024; i += 256) {
        int r = i >> 4, seg = i & 15;
        int gr = rbase + r;
        uint4 v = {0u, 0u, 0u, 0u};
        if (gr < N) v = ((const uint4*)(h2 + (size_t)gr * 128))[seg];
        ((uint4*)(hA + r * AS))[seg] = v;
    }
    __syncthreads();
    int wave = t >> 6, lane = t & 63, l16 = lane & 15, kq = lane >> 4;
    f32x4 acc[8];
#pragma unroll
    for (int i = 0; i < 8; ++i) acc[i] = (f32x4){0.f, 0.f, 0.f, 0.f};
#pragma unroll
    for (int ks = 0; ks < 4; ++ks) {
        int kofs = ks * 32 + kq * 8;
        bf16x8 a = *(const bf16x8*)(hA + (wave * 16 + l16) * AS + kofs);
#pragma unroll
        for (int cb = 0; cb < 8; ++cb) {
            bf16x8 b = *(const bf16x8*)(wB + (cb * 16 + l16) * AS + kofs);
            acc[cb] = __builtin_amdgcn_mfma_f32_16x16x32_bf16(a, b, acc[cb], 0, 0, 0);
        }
    }
    float p[4] = {0.f, 0.f, 0.f, 0.f};
#pragma unroll
    for (int cb = 0; cb < 8; ++cb) {
        int c = cb * 16 + l16;
        float bb = b1[c], w = W2[c];
#pragma unroll
        for (int i = 0; i < 4; ++i) p[i] += fmaxf(acc[cb][i] + bb, 0.f) * w;
    }
#pragma unroll
    for (int i = 0; i < 4; ++i) {
        p[i] += __shfl_xor(p[i], 8, 16);
        p[i] += __shfl_xor(p[i], 4, 16);
        p[i] += __shfl_xor(p[i], 2, 16);
        p[i] += __shfl_xor(p[i], 1, 16);
    }
    if (l16 == 0) {
        int isF32 = *flag;
        float bb = b2[0];
#pragma unroll
        for (int i = 0; i < 4; ++i) {
            int r = rbase + wave * 16 + kq * 4 + i;
            if (r < N)
                store_out(d_out, (size_t)r,
                          1.f / (1.f + __expf(-(p[i] + bb))), isF32);
        }
    }
}

// ===== fused GAT edge pipeline: ONE dst per 64-thread block ===============
__global__ __launch_bounds__(64) void k_gat_fused(
        const __hip_bfloat16* __restrict__ xl,
        const __hip_bfloat16* __restrict__ xr,
        const int* __restrict__ rs, const int2* __restrict__ pk, int N,
        const float* __restrict__ att, const float* __restrict__ bo, int relu,
        float* __restrict__ EX2,
        void* __restrict__ alpha_out, size_t aoff, const int* __restrict__ flag,
        __hip_bfloat16* __restrict__ hout) {
    __shared__ float exsh[CAPD * 4];        // per-dst ex cache (1 KB)
    int lane = threadIdx.x;
    int n = blockIdx.x;
    if (n >= N) return;
    int h = lane >> 4, l16 = lane & 15, c0 = lane * 2;
    unsigned uxr = ((const unsigned*)(xr + (size_t)n * 128))[lane];
    float xr0 = lo16(uxr), xr1 = hi16(uxr);
    // leaky(v)*a = (0.6a)v + (0.4a)|v|  (exact for slope 0.2); log2e folded in
    float a0 = att[c0] * L2E, a1 = att[c0 + 1] * L2E;
    float a06 = 0.6f * a0, a04 = 0.4f * a0;
    float a16 = 0.6f * a1, a14 = 0.4f * a1;
    int beg = __builtin_amdgcn_readfirstlane(rs[n]);
    int end = __builtin_amdgcn_readfirstlane(rs[n + 1]);
    const char* xlb = (const char*)xl;
    const int* pks = (const int*)pk;        // scalar view: pks[2*r+1] = src
    int lb = lane << 2;
    float den = 0.f, acc0 = 0.f, acc1 = 0.f;
    int r = beg;
    __builtin_amdgcn_s_setprio(1);

#define GAT_BATCH(W) { \
    unsigned u[W]; float p[W]; \
    _Pragma("unroll") \
    for (int j = 0; j < W; ++j) { \
        unsigned s = min((unsigned)(pks[((r + j) << 1) | 1] & 0xFFFFF), (unsigned)(N - 1)); \
        u[j] = *(const unsigned*)(xlb + ((size_t)s << 8) + lb); \
    } \
    _Pragma("unroll") \
    for (int j = 0; j < W; ++j) { \
        float v0 = lo16(u[j]) + xr0, v1 = hi16(u[j]) + xr1; \
        float tt = fmaf(fabsf(v0), a04, v0 * a06); \
        tt = fmaf(v1, a16, tt); \
        p[j] = fmaf(fabsf(v1), a14, tt); \
    } \
    _Pragma("unroll") \
    for (int j = 0; j < W; ++j) { \
        p[j] = dpp_add<0x121>(p[j]); \
        p[j] = dpp_add<0x122>(p[j]); \
        p[j] = dpp_add<0x124>(p[j]); \
        p[j] = dpp_add<0x128>(p[j]); \
        p[j] = fexp2(__builtin_amdgcn_fmed3f(p[j], -43.f, 43.f)); \
    } \
    if (l16 == 0) { \
        _Pragma("unroll") \
        for (int j = 0; j < W; ++j) { \
            int idx = r + j - beg; \
            if (idx < CAPD) exsh[idx * 4 + h] = p[j]; \
            else            EX2[(size_t)(r + j) * 4 + h] = p[j]; \
        } \
    } \
    _Pragma("unroll") \
    for (int j = 0; j < W; ++j) { \
        den  += p[j]; \
        acc0 = fmaf(p[j], lo16(u[j]), acc0); \
        acc1 = fmaf(p[j], hi16(u[j]), acc1); \
    } \
    r += W; }

    while (r + 8 <= end) GAT_BATCH(8)
    if (r + 4 <= end) GAT_BATCH(4)
    if (r + 2 <= end) GAT_BATCH(2)
    if (r < end) GAT_BATCH(1)
#undef GAT_BATCH
    __builtin_amdgcn_s_setprio(0);

    float invn = 1.f / fmaxf(den, 1e-30f);
    float v0 = acc0 * invn + bo[c0], v1 = acc1 * invn + bo[c0 + 1];
    if (relu) { v0 = fmaxf(v0, 0.f); v1 = fmaxf(v1, 0.f); }
    __hip_bfloat16 h0 = f2b(v0), h1 = f2b(v1);
    ushort2 st;
    st.x = *(unsigned short*)&h0;
    st.y = *(unsigned short*)&h1;
    ((ushort2*)(hout + (size_t)n * 128))[lane] = st;
    // alpha outputs: 16 edges in parallel, lane (h,l16) handles (r0+l16, h)
    int isF32 = *flag;
    for (int r0 = beg; r0 < end; r0 += 16) {
        int rr = r0 + l16;
        if (rr < end) {
            int idx = rr - beg;
            float ex = (idx < CAPD) ? exsh[idx * 4 + h]
                                    : EX2[(size_t)rr * 4 + h];
            int e = pk[rr].x;
            store_out(alpha_out, aoff + (size_t)e * 4 + h, ex * invn, isF32);
        }
    }
}

extern "C" void kernel_launch(void* const* d_in, const int* in_sizes, int n_in,
                              void* d_out, int out_size, void* d_ws, size_t ws_size,
                              hipStream_t stream) {
    const int* ei = (const int*)d_in[1];
    const int N  = in_sizes[0] / 16;
    const int E  = in_sizes[1] / 2;
    const int ET = E + N;

    // bucket geometry: <=512 buckets (128 nodes/bucket at N=50K)
    int shift = 7;
    while (((N + (1 << shift) - 1) >> shift) > 512) ++shift;
    const int nbkt = (N + (1 << shift) - 1) >> shift;
    const int B1   = (ET + EPB - 1) / EPB;
    const int M    = nbkt * B1;                 // scan length
    const int MB   = (M + 255) / 256;           // scan blocks (<=1024 assumed)

    // ---------------- workspace carve ------------------------------------
    float* P = (float*)d_ws;
    float* encW = P; P += 2048;  float* encb = P; P += 128;
    float* b1l  = P; P += 128;   float* b1r  = P; P += 128;
    float* att1 = P; P += 128;   float* bo1  = P; P += 128;
    float* b2l  = P; P += 128;   float* b2r  = P; P += 128;
    float* att2 = P; P += 128;   float* bo2  = P; P += 128;
    float* mb1  = P; P += 128;   float* mW2  = P; P += 128;
    float* mb2  = P; P += 4;
    int*  FLAG  = (int*)P; P += 4;
    int*  RS    = (int*)P; P += N + 1;
    int*  GCNT  = (int*)P; P += M;
    int*  OFFS  = (int*)P; P += M;
    int*  BSUM  = (int*)P; P += MB;
    P = (float*)(((uintptr_t)P + 7) & ~(uintptr_t)7);     // 8B align
    int2* PK    = (int2*)P; P += (size_t)ET * 2;          // packed (e, src)
    float* EX2  = P; P += (size_t)ET * 4;
    // staging aliases EX2 (only live before the GAT kernels run):
    int2* STG   = (int2*)EX2;                             // ET packed records
    // 256-align the bf16 matrix region (256 B feature rows = 2 cache lines)
    P = (float*)(((uintptr_t)P + 255) & ~(uintptr_t)255);
    __hip_bfloat16* W1Lt = (__hip_bfloat16*)P;            // 5 x 128*128 bf16
    __hip_bfloat16* W1Rt = W1Lt + 16384;
    __hip_bfloat16* W2Lt = W1Rt + 16384;
    __hip_bfloat16* W2Rt = W2Lt + 16384;
    __hip_bfloat16* MW1t = W2Rt + 16384;
    __hip_bfloat16* Hb   = MW1t + 16384;                  // N*128 bf16 (256B-aligned)
    __hip_bfloat16* XL   = Hb + (size_t)N * 128;
    __hip_bfloat16* XR   = XL + (size_t)N * 128;

    // ---------------- fused preprocessing (1 launch) ----------------------
    CvtTab tab;
    const int srcIdx[NCVT] = {4, 5, 7, 9, 10, 11, 13, 15, 16, 17, 19, 20, 21};
    float* dsts[NCVT] = {encW, encb, b1l, b1r, att1, bo1, b2l, b2r, att2, bo2, mb1, mW2, mb2};
    const int ns[NCVT] = {2048, 128, 128, 128, 128, 128, 128, 128, 128, 128, 128, 128, 1};
    int tot = 0;
    for (int i = 0; i < NCVT; ++i) {
        tab.src[i] = d_in[srcIdx[i]];
        tab.dst[i] = dsts[i];
        tab.n[i] = ns[i];
        tot += ns[i];
    }
    tab.total = tot;
    WtTab wt;
    wt.src[0] = d_in[6];  wt.dst[0] = W1Lt;
    wt.src[1] = d_in[8];  wt.dst[1] = W1Rt;
    wt.src[2] = d_in[12]; wt.dst[2] = W2Lt;
    wt.src[3] = d_in[14]; wt.dst[3] = W2Rt;
    wt.src[4] = d_in[18]; wt.dst[4] = MW1t;
    const unsigned short* det = (const unsigned short*)d_in[4];  // enc_W raw
    const int preGrid = B1 + 80 + (tot + 1023) / 1024;
    k_pre<<<preGrid, 1024, 0, stream>>>(ei, E, ET, N, shift, nbkt, B1, GCNT,
                                        tab, wt, det, FLAG);

    // ---------------- CSR by dst + layer-1 GEMM (overlapped) ---------------
    const int gGrid = (N + 63) / 64;
    k_scanA<<<MB, 256, 0, stream>>>(GCNT, M, OFFS, BSUM);
    k_binB<<<B1, 256, 0, stream>>>(ei, E, ET, N, shift, nbkt, B1, OFFS, BSUM, MB, STG);
    k_csr_gemm<<<nbkt + gGrid, 256, 0, stream>>>(
        STG, OFFS, BSUM, MB, N, shift, B1, nbkt, RS, PK,
        d_in[0], encW, encb, FLAG, W1Lt, b1l, W1Rt, b1r, XL, XR);

    const size_t a1_off = (size_t)N;
    const size_t a2_off = (size_t)N + (size_t)ET * 4;

    // ---- GAT layer 1 ----
    k_gat_fused<<<N, 64, 0, stream>>>(XL, XR, RS, PK, N, att1, bo1, 1,
                                      EX2, d_out, a1_off, FLAG, Hb);

    // ---- GAT layer 2 ----
    k_gemm2_mfma<<<gGrid, 256, 0, stream>>>(Hb, W2Lt, b2l, W2Rt, b2r, N, XL, XR);
    k_gat_fused<<<N, 64, 0, stream>>>(XL, XR, RS, PK, N, att2, bo2, 0,
                                      EX2, d_out, a2_off, FLAG, Hb);

    k_mlp_mfma<<<gGrid, 256, 0, stream>>>(Hb, MW1t, mb1, mW2, mb2, N, d_out, FLAG);
}